// Round 4
// baseline (31.548 us; speedup 1.0000x reference)
//
#include <hip/hip_runtime.h>
#include <hip/hip_bf16.h>
#include <math.h>

typedef __bf16 bf16_t;
typedef __attribute__((ext_vector_type(8))) __bf16 bf16x8;
typedef __attribute__((ext_vector_type(4))) float f32x4;

#define NN 2048
#define CC 256
#define BB 16
#define COLS 4096          // flattened (b,c)

// Three sub-transforms (out[k], k=0..2047):
//  EE: out[4i]   = sum_{p=0}^{256} ee[p] cos(2pi*p*i/512),       i=0..255 (+mirror 2048-4i; k=1024 in prep)
//  EO: out[4i+2] = sum_{m=0}^{255} eo[m] cos(2pi*m*(2i+1)/1024), i=0..255 (+mirror 2046-4i)
//  O : out[2j+1] = sum_{m=0}^{511} o[m]  cos(2pi*m*(2j+1)/2048), j=0..511 (+mirror 2047-2j)
#define KEE 320            // 257 padded to 5*64 (p>256 zero both sides)
#define MEE 256
#define KEO 256
#define MEO 256
#define KO  512
#define MO  512

#define ANG2 (6.283185307179586f / 2048.0f)
#define ANG1 (6.283185307179586f / 1024.0f)
#define ANG0 (6.283185307179586f / 512.0f)

__device__ __forceinline__ void gload_lds16(const void* g, void* l) {
    __builtin_amdgcn_global_load_lds(
        (const __attribute__((address_space(1))) void*)g,
        (__attribute__((address_space(3))) void*)l, 16, 0, 0);
}

// ---------------- prologue: A-build + read-x-once fold ----------------
#define NBLK_AEE 10        // 256 rows * 40 chunks / 1024
#define NBLK_AEO 8         // 256 * 32 / 1024
#define NBLK_AO  32        // 512 * 64 / 1024
#define NBLK_A   (NBLK_AEE + NBLK_AEO + NBLK_AO)
#define NBLK_FOLD 128      // 32 cols each
#define PREP_BLOCKS (NBLK_A + NBLK_FOLD)

union V8 { bf16_t h[8]; uint4 v; };

__global__ __launch_bounds__(1024) void prep_kernel(
    const float* __restrict__ x,
    bf16_t* __restrict__ Aee, bf16_t* __restrict__ Aeo, bf16_t* __restrict__ Ao,
    bf16_t* __restrict__ Yee, bf16_t* __restrict__ Yeo, bf16_t* __restrict__ Yo,
    float* __restrict__ out)
{
    __shared__ bf16_t e_lds[32][522];   // e[m], m=0..512, col-major per 32-col slice
    __shared__ bf16_t o_lds[32][522];   // o[m], m=0..511
    __shared__ float red[32][33];
    const int blk = blockIdx.x;
    const int t = threadIdx.x;

    if (blk < NBLK_AEE) {              // Aee[i][p] = cos(2pi*p*i/512), zero p>256
        const int u = blk * 1024 + t;  // 0..10239
        const int i = u / 40;
        const int p0 = (u - i * 40) * 8;
        const unsigned step = (unsigned)i & 511u;
        unsigned ph = ((unsigned)i * (unsigned)p0) & 511u;
        V8 vals;
#pragma unroll
        for (int q = 0; q < 8; ++q) {
            vals.h[q] = (p0 + q <= 256) ? (bf16_t)cosf((float)ph * ANG0) : (bf16_t)0.0f;
            ph = (ph + step) & 511u;
        }
        *reinterpret_cast<uint4*>(Aee + (size_t)i * KEE + p0) = vals.v;
        return;
    }
    if (blk < NBLK_AEE + NBLK_AEO) {   // Aeo[i][m] = cos(2pi*m*(2i+1)/1024)
        const int u = (blk - NBLK_AEE) * 1024 + t;
        const int i = u >> 5;
        const int m0 = (u & 31) * 8;
        const unsigned tw = 2u * (unsigned)i + 1u;
        unsigned ph = ((unsigned)m0 * tw) & 1023u;
        V8 vals;
#pragma unroll
        for (int q = 0; q < 8; ++q) {
            vals.h[q] = (bf16_t)cosf((float)ph * ANG1);
            ph = (ph + tw) & 1023u;
        }
        *reinterpret_cast<uint4*>(Aeo + (size_t)i * KEO + m0) = vals.v;
        return;
    }
    if (blk < NBLK_A) {                // Ao[j][m] = cos(2pi*m*(2j+1)/2048)
        const int u = (blk - NBLK_AEE - NBLK_AEO) * 1024 + t;
        const int j = u >> 6;
        const int m0 = (u & 63) * 8;
        const unsigned tw = 2u * (unsigned)j + 1u;
        unsigned ph = ((unsigned)m0 * tw) & 2047u;
        V8 vals;
#pragma unroll
        for (int q = 0; q < 8; ++q) {
            vals.h[q] = (bf16_t)cosf((float)ph * ANG2);
            ph = (ph + tw) & 2047u;
        }
        *reinterpret_cast<uint4*>(Ao + (size_t)j * KO + m0) = vals.v;
        return;
    }

    // ---- fold: this block owns 32 consecutive global columns ----
    const int fb = blk - NBLK_A;       // 0..127
    const int gc0 = fb * 32;
    const int b = gc0 >> 8;
    const int c0 = gc0 & 255;
    const int tx = t & 31;             // col within slice
    const int ty = t >> 5;             // 0..31
    const float* xb = x + (size_t)b * NN * CC + c0;

    // e[m] = w*(x[m]+x[1024+m]+x[1024-m]+x[2048-m]),  w=.5 at m=0,512
    // o[m] = w0*((x[m]-x[1024+m]) - (x[1024-m]-x[2048-m])), w0=.5 at m=0
    for (int m0 = 0; m0 <= 512; m0 += 32) {
        const int m = m0 + ty;
        if (m <= 512) {
            const int r2 = 1024 - m, r3 = 1024 + m, r4 = (2048 - m) & 2047;
            const float x1 = xb[(size_t)m  * CC + tx];
            const float x2 = xb[(size_t)r2 * CC + tx];
            const float x3 = xb[(size_t)r3 * CC + tx];
            const float x4 = xb[(size_t)r4 * CC + tx];
            const float w = (m == 0 || m == 512) ? 0.5f : 1.0f;
            e_lds[tx][m] = (bf16_t)(w * ((x1 + x3) + (x2 + x4)));
            if (m <= 511) {
                const float w0 = (m == 0) ? 0.5f : 1.0f;
                o_lds[tx][m] = (bf16_t)(w0 * ((x1 - x3) - (x2 - x4)));
            }
        }
    }
    __syncthreads();

    // out[b][1024][c] = sum_p (-1)^p ee[p]   (EE row i=256, done here)
    {
        float part = 0.f;
        for (int p = ty; p <= 256; p += 32) {
            float ee;
            if (p == 0) ee = (float)e_lds[tx][0] + (float)e_lds[tx][512];
            else if (p < 256) ee = (float)e_lds[tx][p] + (float)e_lds[tx][512 - p];
            else ee = (float)e_lds[tx][256];
            part += ee;
        }
        red[ty][tx] = (ty & 1) ? -part : part;   // (-1)^p = (-1)^ty (stride 32)
    }
    __syncthreads();
    if (t < 32) {
        float tot = 0.f;
#pragma unroll
        for (int s = 0; s < 32; ++s) tot += red[s][t];
        out[(size_t)b * NN * CC + (size_t)1024 * CC + c0 + t] = tot;
    }

    // write Yee (40 chunks), Yeo (32), Yo (64) per col; 16B/lane stores
    for (int idx = t; idx < 32 * 136; idx += 1024) {
        const int col = idx & 31;
        const int ch = idx >> 5;
        V8 vals;
        bf16_t* dst;
        if (ch < 40) {
            const int p0 = ch * 8;
#pragma unroll
            for (int q = 0; q < 8; ++q) {
                const int p = p0 + q;
                float v;
                if (p == 0) v = (float)e_lds[col][0] + (float)e_lds[col][512];
                else if (p < 256) v = (float)e_lds[col][p] + (float)e_lds[col][512 - p];
                else if (p == 256) v = (float)e_lds[col][256];
                else v = 0.f;
                vals.h[q] = (bf16_t)v;
            }
            dst = Yee + (size_t)(gc0 + col) * KEE + p0;
        } else if (ch < 72) {
            const int m0 = (ch - 40) * 8;
#pragma unroll
            for (int q = 0; q < 8; ++q) {
                const int m = m0 + q;
                const float v = (m == 0)
                    ? (float)e_lds[col][0] - (float)e_lds[col][512]
                    : (float)e_lds[col][m] - (float)e_lds[col][512 - m];
                vals.h[q] = (bf16_t)v;
            }
            dst = Yeo + (size_t)(gc0 + col) * KEO + m0;
        } else {
            const int m0 = (ch - 72) * 8;
#pragma unroll
            for (int q = 0; q < 8; ++q) vals.h[q] = o_lds[col][m0 + q];
            dst = Yo + (size_t)(gc0 + col) * KO + m0;
        }
        *reinterpret_cast<uint4*>(dst) = vals.v;
    }
}

// ---------------- triple GEMM, one launch ----------------
// grid (64, 12): y 0..3 EE (BM=64), 4..7 EO (BM=64), 8..11 O (BM=128). BN=64.

__global__ __launch_bounds__(256) void gemm_kernel(
    const bf16_t* __restrict__ Aee, const bf16_t* __restrict__ Aeo,
    const bf16_t* __restrict__ Ao,
    const bf16_t* __restrict__ Yee, const bf16_t* __restrict__ Yeo,
    const bf16_t* __restrict__ Yo, float* __restrict__ out)
{
    __shared__ bf16_t As[128 * 64];
    __shared__ bf16_t Bs[64 * 64];

    const int col0 = blockIdx.x * 64;
    const int yb = blockIdx.y;

    const bf16_t *Ab, *Bb;
    int row0, kdim, half;
    if (yb < 4)      { half = 0; row0 = yb * 64;        kdim = KEE; Ab = Aee + (size_t)row0 * KEE; Bb = Yee + (size_t)col0 * KEE; }
    else if (yb < 8) { half = 1; row0 = (yb - 4) * 64;  kdim = KEO; Ab = Aeo + (size_t)row0 * KEO; Bb = Yeo + (size_t)col0 * KEO; }
    else             { half = 2; row0 = (yb - 8) * 128; kdim = KO;  Ab = Ao  + (size_t)row0 * KO;  Bb = Yo  + (size_t)col0 * KO; }
    const int ksteps = kdim >> 6;

    const int t = threadIdx.x;
    const int lane = t & 63;
    const int wid = t >> 6;
    const int wr = wid >> 1, wc = wid & 1;
    const int srow = t >> 3;
    const int scol = (t & 7) * 8;
    const int lrow = lane & 15;
    const int rgrp = lane >> 4;
    const int cl = lane & 15;

    if (half == 2) {                   // ---- O: BM=128 ----
        f32x4 acc[4][2] = {};
        for (int kt = 0; kt < 8; ++kt) {
            const int k0 = kt * 64;
            __syncthreads();
#pragma unroll
            for (int it = 0; it < 4; ++it) {
                const int r = srow + it * 32;
                gload_lds16(Ab + (size_t)r * KO + k0 + scol, As + r * 64 + scol);
            }
#pragma unroll
            for (int it = 0; it < 2; ++it) {
                const int r = srow + it * 32;
                gload_lds16(Bb + (size_t)r * KO + k0 + scol, Bs + r * 64 + scol);
            }
            __syncthreads();
#pragma unroll
            for (int kk = 0; kk < 64; kk += 32) {
                const int koff = kk + (lane >> 4) * 8;
                bf16x8 af[4], bfr[2];
#pragma unroll
                for (int m = 0; m < 4; ++m)
                    af[m] = *(const bf16x8*)&As[(wr * 64 + m * 16 + lrow) * 64 + koff];
#pragma unroll
                for (int n = 0; n < 2; ++n)
                    bfr[n] = *(const bf16x8*)&Bs[(wc * 32 + n * 16 + lrow) * 64 + koff];
#pragma unroll
                for (int m = 0; m < 4; ++m)
#pragma unroll
                    for (int n = 0; n < 2; ++n)
                        acc[m][n] = __builtin_amdgcn_mfma_f32_16x16x32_bf16(
                            af[m], bfr[n], acc[m][n], 0, 0, 0);
            }
        }
#pragma unroll
        for (int m = 0; m < 4; ++m)
#pragma unroll
            for (int n = 0; n < 2; ++n) {
                const int col = col0 + wc * 32 + n * 16 + cl;
                float* obc = out + (size_t)(col >> 8) * NN * CC + (col & 255);
#pragma unroll
                for (int r = 0; r < 4; ++r) {
                    const int j = row0 + wr * 64 + m * 16 + rgrp * 4 + r;
                    const float v = acc[m][n][r];
                    obc[(size_t)(2 * j + 1) * CC] = v;
                    obc[(size_t)(2047 - 2 * j) * CC] = v;
                }
            }
    } else {                           // ---- EE / EO: BM=64 ----
        f32x4 acc[2][2] = {};
        for (int kt = 0; kt < ksteps; ++kt) {
            const int k0 = kt * 64;
            __syncthreads();
#pragma unroll
            for (int it = 0; it < 2; ++it) {
                const int r = srow + it * 32;
                gload_lds16(Ab + (size_t)r * kdim + k0 + scol, As + r * 64 + scol);
                gload_lds16(Bb + (size_t)r * kdim + k0 + scol, Bs + r * 64 + scol);
            }
            __syncthreads();
#pragma unroll
            for (int kk = 0; kk < 64; kk += 32) {
                const int koff = kk + (lane >> 4) * 8;
                bf16x8 af[2], bfr[2];
#pragma unroll
                for (int m = 0; m < 2; ++m)
                    af[m] = *(const bf16x8*)&As[(wr * 32 + m * 16 + lrow) * 64 + koff];
#pragma unroll
                for (int n = 0; n < 2; ++n)
                    bfr[n] = *(const bf16x8*)&Bs[(wc * 32 + n * 16 + lrow) * 64 + koff];
#pragma unroll
                for (int m = 0; m < 2; ++m)
#pragma unroll
                    for (int n = 0; n < 2; ++n)
                        acc[m][n] = __builtin_amdgcn_mfma_f32_16x16x32_bf16(
                            af[m], bfr[n], acc[m][n], 0, 0, 0);
            }
        }
#pragma unroll
        for (int m = 0; m < 2; ++m)
#pragma unroll
            for (int n = 0; n < 2; ++n) {
                const int col = col0 + wc * 32 + n * 16 + cl;
                float* obc = out + (size_t)(col >> 8) * NN * CC + (col & 255);
#pragma unroll
                for (int r = 0; r < 4; ++r) {
                    const int i = row0 + wr * 32 + m * 16 + rgrp * 4 + r;  // 0..255
                    const float v = acc[m][n][r];
                    if (half == 0) {
                        obc[(size_t)(4 * i) * CC] = v;
                        if (i >= 1) obc[(size_t)(2048 - 4 * i) * CC] = v;
                    } else {
                        obc[(size_t)(4 * i + 2) * CC] = v;
                        obc[(size_t)(2046 - 4 * i) * CC] = v;
                    }
                }
            }
    }
}

// ---------------- fallback (no/small ws): correct but slow ----------------

__global__ void fallback_kernel(const float* __restrict__ x, float* __restrict__ out) {
    __shared__ float tbl[NN];
    const int b = blockIdx.y;
    const int kbase = blockIdx.x * 16;
    const int t = threadIdx.x;  // 256 = C
    for (int i = t; i < NN; i += 256)
        tbl[i] = cosf((float)i * ANG2);
    __syncthreads();
    float acc[16];
#pragma unroll
    for (int kk = 0; kk < 16; ++kk) acc[kk] = 0.f;
    const float* xb = x + (size_t)b * NN * CC;
    for (int n = 0; n < NN; ++n) {
        const float xv = xb[(size_t)n * CC + t];
#pragma unroll
        for (int kk = 0; kk < 16; ++kk) {
            const int m = (n * (kbase + kk)) & (NN - 1);
            acc[kk] += tbl[m] * xv;
        }
    }
#pragma unroll
    for (int kk = 0; kk < 16; ++kk)
        out[((size_t)b * NN + kbase + kk) * CC + t] = acc[kk];
}

extern "C" void kernel_launch(void* const* d_in, const int* in_sizes, int n_in,
                              void* d_out, int out_size, void* d_ws, size_t ws_size,
                              hipStream_t stream) {
    const float* x = (const float*)d_in[0];
    float* out = (float*)d_out;

    const size_t Aee_b = (size_t)MEE * KEE * 2;      // 163,840
    const size_t Aeo_b = (size_t)MEO * KEO * 2;      // 131,072
    const size_t Ao_b  = (size_t)MO  * KO  * 2;      // 524,288
    const size_t Yee_b = (size_t)COLS * KEE * 2;     // 2,621,440
    const size_t Yeo_b = (size_t)COLS * KEO * 2;     // 2,097,152
    const size_t Yo_b  = (size_t)COLS * KO  * 2;     // 4,194,304
    const size_t need = Aee_b + Aeo_b + Ao_b + Yee_b + Yeo_b + Yo_b;

    if (ws_size >= need) {
        char* p = (char*)d_ws;
        bf16_t* Aee = (bf16_t*)p;              p += Aee_b;
        bf16_t* Aeo = (bf16_t*)p;              p += Aeo_b;
        bf16_t* Ao  = (bf16_t*)p;              p += Ao_b;
        bf16_t* Yee = (bf16_t*)p;              p += Yee_b;
        bf16_t* Yeo = (bf16_t*)p;              p += Yeo_b;
        bf16_t* Yo  = (bf16_t*)p;
        prep_kernel<<<PREP_BLOCKS, 1024, 0, stream>>>(x, Aee, Aeo, Ao, Yee, Yeo, Yo, out);
        gemm_kernel<<<dim3(COLS / 64, 12), 256, 0, stream>>>(Aee, Aeo, Ao, Yee, Yeo, Yo, out);
    } else {
        fallback_kernel<<<dim3(NN / 16, BB), CC, 0, stream>>>(x, out);
    }
}

// Round 5
// 28.187 us; speedup vs baseline: 1.1193x; 1.1193x over previous
//
#include <hip/hip_runtime.h>
#include <hip/hip_bf16.h>
#include <math.h>

typedef __bf16 bf16_t;
typedef __attribute__((ext_vector_type(8))) __bf16 bf16x8;
typedef __attribute__((ext_vector_type(4))) float f32x4;

#define NN 2048
#define CC 256
#define BB 16
#define COLS 4096          // flattened (b,c)

// Sub-transforms (out[k], k=0..2047):
//  EE: out[4i]   = sum_{p=0}^{256} ee[p] cos(2pi*p*i/512),       i=0..255 (+mirror 2048-4i; k=1024 via GEMV)
//  EO: out[4i+2] = sum_{m=0}^{255} eo[m] cos(2pi*m*(2i+1)/1024), i=0..255 (+mirror 2046-4i)
//  O : out[2j+1] = sum_{m=0}^{511} o[m]  cos(2pi*m*(2j+1)/2048), j=0..511 (+mirror 2047-2j)
//  O K-axis is PERMUTED: u<256 -> m=u ; u==256 -> m=256 ; u>256 -> m=768-u
#define KEE 320            // 257 padded to 5*64
#define MEE 256
#define KEO 256
#define KO  512

#define ANG2 (6.283185307179586f / 2048.0f)
#define ANG1 (6.283185307179586f / 1024.0f)
#define ANG0 (6.283185307179586f / 512.0f)

__device__ __forceinline__ void gload_lds16(const void* g, void* l) {
    __builtin_amdgcn_global_load_lds(
        (const __attribute__((address_space(1))) void*)g,
        (__attribute__((address_space(3))) void*)l, 16, 0, 0);
}

union V8 { bf16_t h[8]; uint4 v; };

// ---------------- prologue: A-build + register-only fold ----------------
// blocks: [0,40) Aee | [40,72) Aeo | [72,200) Ao | [200,712) fold | [712,776) p=256
#define NBLK_AEE 40
#define NBLK_AEO 32
#define NBLK_AO  128
#define NBLK_A   (NBLK_AEE + NBLK_AEO + NBLK_AO)
#define NBLK_FOLD 512
#define PREP_BLOCKS (NBLK_A + NBLK_FOLD + 64)

__global__ __launch_bounds__(256) void prep_kernel(
    const float* __restrict__ x,
    bf16_t* __restrict__ Aee, bf16_t* __restrict__ Aeo, bf16_t* __restrict__ Ao,
    bf16_t* __restrict__ Yee, bf16_t* __restrict__ Yeo, bf16_t* __restrict__ Yo)
{
    const int blk = blockIdx.x;
    const int t = threadIdx.x;

    if (blk < NBLK_AEE) {              // Aee[i][p] = cos(2pi*p*i/512), zero p>256
        const int u = blk * 256 + t;   // 0..10239
        const int i = u / 40;
        const int p0 = (u - i * 40) * 8;
        const unsigned step = (unsigned)i & 511u;
        unsigned ph = ((unsigned)i * (unsigned)p0) & 511u;
        V8 vals;
#pragma unroll
        for (int q = 0; q < 8; ++q) {
            vals.h[q] = (p0 + q <= 256) ? (bf16_t)cosf((float)ph * ANG0) : (bf16_t)0.0f;
            ph = (ph + step) & 511u;
        }
        *reinterpret_cast<uint4*>(Aee + (size_t)i * KEE + p0) = vals.v;
        return;
    }
    if (blk < NBLK_AEE + NBLK_AEO) {   // Aeo[i][m] = cos(2pi*m*(2i+1)/1024)
        const int u = (blk - NBLK_AEE) * 256 + t;
        const int i = u >> 5;
        const int m0 = (u & 31) * 8;
        const unsigned tw = 2u * (unsigned)i + 1u;
        unsigned ph = ((unsigned)m0 * tw) & 1023u;
        V8 vals;
#pragma unroll
        for (int q = 0; q < 8; ++q) {
            vals.h[q] = (bf16_t)cosf((float)ph * ANG1);
            ph = (ph + tw) & 1023u;
        }
        *reinterpret_cast<uint4*>(Aeo + (size_t)i * KEO + m0) = vals.v;
        return;
    }
    if (blk < NBLK_A) {                // Ao[j][u] = cos(2pi*m(u)*(2j+1)/2048)
        const int u = (blk - NBLK_AEE - NBLK_AEO) * 256 + t;
        const int j = u >> 6;
        const int u0 = (u & 63) * 8;
        const unsigned tw = 2u * (unsigned)j + 1u;
        V8 vals;
#pragma unroll
        for (int q = 0; q < 8; ++q) {
            const int uu = u0 + q;
            const int m = (uu <= 256) ? uu : (768 - uu);
            const unsigned ph = ((unsigned)m * tw) & 2047u;
            vals.h[q] = (bf16_t)cosf((float)ph * ANG2);
        }
        *reinterpret_cast<uint4*>(Ao + (size_t)j * KO + u0) = vals.v;
        return;
    }

    if (blk < NBLK_A + NBLK_FOLD) {
        // ---- fold: (p-tile, col-tile), all register, all aligned ----
        const int f = blk - NBLK_A;
        const int pt = f >> 6;             // 0..7
        const int ct = f & 63;             // 0..63
        const int gc0 = ct * 64;
        const int col = t & 63;
        const int pg = t >> 6;             // wave id 0..3
        const int p_base = pt * 32 + pg * 8;
        const float* xcol = x + (size_t)(gc0 >> 8) * NN * CC + (gc0 & 255) + col;

        float eeV[8], eoV[8], olV[8], ohV[8];
#pragma unroll
        for (int q = 0; q < 8; ++q) {
            const int p = p_base + q;
            const int n2 = 512 - p, n3 = 512 + p, n4 = 1024 - p;
            const int n5 = 1024 + p, n6 = 1536 - p, n7 = 1536 + p;
            const int n8 = (2048 - p) & 2047;
            const float x1 = xcol[(size_t)p  * CC];
            const float x2 = xcol[(size_t)n2 * CC];
            const float x3 = xcol[(size_t)n3 * CC];
            const float x4 = xcol[(size_t)n4 * CC];
            const float x5 = xcol[(size_t)n5 * CC];
            const float x6 = xcol[(size_t)n6 * CC];
            const float x7 = xcol[(size_t)n7 * CC];
            const float x8 = xcol[(size_t)n8 * CC];
            const float w = (p == 0) ? 0.5f : 1.0f;
            const float e_lo = w * ((x1 + x4) + (x5 + x8));
            const float e_hi = w * ((x2 + x3) + (x6 + x7));
            olV[q] = w * ((x1 - x5) - (x4 - x8));
            ohV[q] = (x2 - x6) - (x3 - x7);       // o[512-p] -> slot u=256+p
            eeV[q] = e_lo + e_hi;
            eoV[q] = e_lo - e_hi;
        }
        if (pt == 0 && pg == 0) {
            // p==0 lane: oh slot u=256 must carry o[256] (o[512] doesn't exist)
            const float a = xcol[(size_t)256  * CC];
            const float b2 = xcol[(size_t)768  * CC];
            const float c = xcol[(size_t)1280 * CC];
            const float d = xcol[(size_t)1792 * CC];
            ohV[0] = (a - c) - (b2 - d);          // x256 - x1280 - x768 + x1792
        }
        V8 vee, veo, vol, voh;
#pragma unroll
        for (int q = 0; q < 8; ++q) {
            vee.h[q] = (bf16_t)eeV[q]; veo.h[q] = (bf16_t)eoV[q];
            vol.h[q] = (bf16_t)olV[q]; voh.h[q] = (bf16_t)ohV[q];
        }
        const size_t gcol = (size_t)(gc0 + col);
        *reinterpret_cast<uint4*>(Yee + gcol * KEE + p_base) = vee.v;
        *reinterpret_cast<uint4*>(Yeo + gcol * KEO + p_base) = veo.v;
        *reinterpret_cast<uint4*>(Yo  + gcol * KO  + p_base) = vol.v;
        *reinterpret_cast<uint4*>(Yo  + gcol * KO  + 256 + p_base) = voh.v;
        return;
    }

    // ---- p=256 tile: ee[256] + zero-fill Yee[257..319] ----
    {
        const int ct = blk - (NBLK_A + NBLK_FOLD);
        if (t >= 64) return;
        const int gc0 = ct * 64;
        const float* xcol = x + (size_t)(gc0 >> 8) * NN * CC + (gc0 & 255) + t;
        const float ee256 = (xcol[(size_t)256 * CC] + xcol[(size_t)768 * CC]) +
                            (xcol[(size_t)1280 * CC] + xcol[(size_t)1792 * CC]);
        bf16_t* base = Yee + (size_t)(gc0 + t) * KEE + 256;
        V8 z; z.v = make_uint4(0, 0, 0, 0);
        V8 first = z; first.h[0] = (bf16_t)ee256;
        *reinterpret_cast<uint4*>(base) = first.v;
#pragma unroll
        for (int ch = 1; ch < 8; ++ch)
            *reinterpret_cast<uint4*>(base + ch * 8) = z.v;
    }
}

// ---------------- triple GEMM + GEMV, one launch ----------------
// grid (64, 13): y 0..3 EE (BM=64), 4..7 EO (BM=64), 8..11 O (BM=128), 12 GEMV k=1024.

__global__ __launch_bounds__(256) void gemm_kernel(
    const bf16_t* __restrict__ Aee, const bf16_t* __restrict__ Aeo,
    const bf16_t* __restrict__ Ao,
    const bf16_t* __restrict__ Yee, const bf16_t* __restrict__ Yeo,
    const bf16_t* __restrict__ Yo, float* __restrict__ out)
{
    __shared__ bf16_t As[128 * 64];
    __shared__ bf16_t Bs[64 * 64];
    __shared__ float red[64][4];

    const int col0 = blockIdx.x * 64;
    const int yb = blockIdx.y;
    const int t = threadIdx.x;

    if (yb == 12) {                    // ---- GEMV: out[1024][c] = sum (-1)^p ee[p]
        const int col = t & 63;
        const int part = t >> 6;
        const bf16_t* yc = Yee + (size_t)(col0 + col) * KEE + part * 80;
        float s = 0.f;
#pragma unroll
        for (int jc = 0; jc < 10; ++jc) {
            const bf16x8 v = *reinterpret_cast<const bf16x8*>(yc + jc * 8);
#pragma unroll
            for (int q = 0; q < 8; ++q)
                s += (q & 1) ? -(float)v[q] : (float)v[q];
        }
        red[col][part] = s;
        __syncthreads();
        if (t < 64) {
            const float tot = (red[t][0] + red[t][1]) + (red[t][2] + red[t][3]);
            const int gc = col0 + t;
            out[(size_t)(gc >> 8) * NN * CC + (size_t)1024 * CC + (gc & 255)] = tot;
        }
        return;
    }

    const bf16_t *Ab, *Bb;
    int row0, kdim, half;
    if (yb < 4)      { half = 0; row0 = yb * 64;        kdim = KEE; Ab = Aee + (size_t)row0 * KEE; Bb = Yee + (size_t)col0 * KEE; }
    else if (yb < 8) { half = 1; row0 = (yb - 4) * 64;  kdim = KEO; Ab = Aeo + (size_t)row0 * KEO; Bb = Yeo + (size_t)col0 * KEO; }
    else             { half = 2; row0 = (yb - 8) * 128; kdim = KO;  Ab = Ao  + (size_t)row0 * KO;  Bb = Yo  + (size_t)col0 * KO; }
    const int ksteps = kdim >> 6;

    const int lane = t & 63;
    const int wid = t >> 6;
    const int wr = wid >> 1, wc = wid & 1;
    const int srow = t >> 3;
    const int scol = (t & 7) * 8;
    const int lrow = lane & 15;
    const int rgrp = lane >> 4;
    const int cl = lane & 15;

    if (half == 2) {                   // ---- O: BM=128 ----
        f32x4 acc[4][2] = {};
        for (int kt = 0; kt < 8; ++kt) {
            const int k0 = kt * 64;
            __syncthreads();
#pragma unroll
            for (int it = 0; it < 4; ++it) {
                const int r = srow + it * 32;
                gload_lds16(Ab + (size_t)r * KO + k0 + scol, As + r * 64 + scol);
            }
#pragma unroll
            for (int it = 0; it < 2; ++it) {
                const int r = srow + it * 32;
                gload_lds16(Bb + (size_t)r * KO + k0 + scol, Bs + r * 64 + scol);
            }
            __syncthreads();
#pragma unroll
            for (int kk = 0; kk < 64; kk += 32) {
                const int koff = kk + (lane >> 4) * 8;
                bf16x8 af[4], bfr[2];
#pragma unroll
                for (int m = 0; m < 4; ++m)
                    af[m] = *(const bf16x8*)&As[(wr * 64 + m * 16 + lrow) * 64 + koff];
#pragma unroll
                for (int n = 0; n < 2; ++n)
                    bfr[n] = *(const bf16x8*)&Bs[(wc * 32 + n * 16 + lrow) * 64 + koff];
#pragma unroll
                for (int m = 0; m < 4; ++m)
#pragma unroll
                    for (int n = 0; n < 2; ++n)
                        acc[m][n] = __builtin_amdgcn_mfma_f32_16x16x32_bf16(
                            af[m], bfr[n], acc[m][n], 0, 0, 0);
            }
        }
#pragma unroll
        for (int m = 0; m < 4; ++m)
#pragma unroll
            for (int n = 0; n < 2; ++n) {
                const int col = col0 + wc * 32 + n * 16 + cl;
                float* obc = out + (size_t)(col >> 8) * NN * CC + (col & 255);
#pragma unroll
                for (int r = 0; r < 4; ++r) {
                    const int j = row0 + wr * 64 + m * 16 + rgrp * 4 + r;
                    const float v = acc[m][n][r];
                    obc[(size_t)(2 * j + 1) * CC] = v;
                    obc[(size_t)(2047 - 2 * j) * CC] = v;
                }
            }
    } else {                           // ---- EE / EO: BM=64 ----
        f32x4 acc[2][2] = {};
        for (int kt = 0; kt < ksteps; ++kt) {
            const int k0 = kt * 64;
            __syncthreads();
#pragma unroll
            for (int it = 0; it < 2; ++it) {
                const int r = srow + it * 32;
                gload_lds16(Ab + (size_t)r * kdim + k0 + scol, As + r * 64 + scol);
                gload_lds16(Bb + (size_t)r * kdim + k0 + scol, Bs + r * 64 + scol);
            }
            __syncthreads();
#pragma unroll
            for (int kk = 0; kk < 64; kk += 32) {
                const int koff = kk + (lane >> 4) * 8;
                bf16x8 af[2], bfr[2];
#pragma unroll
                for (int m = 0; m < 2; ++m)
                    af[m] = *(const bf16x8*)&As[(wr * 32 + m * 16 + lrow) * 64 + koff];
#pragma unroll
                for (int n = 0; n < 2; ++n)
                    bfr[n] = *(const bf16x8*)&Bs[(wc * 32 + n * 16 + lrow) * 64 + koff];
#pragma unroll
                for (int m = 0; m < 2; ++m)
#pragma unroll
                    for (int n = 0; n < 2; ++n)
                        acc[m][n] = __builtin_amdgcn_mfma_f32_16x16x32_bf16(
                            af[m], bfr[n], acc[m][n], 0, 0, 0);
            }
        }
#pragma unroll
        for (int m = 0; m < 2; ++m)
#pragma unroll
            for (int n = 0; n < 2; ++n) {
                const int col = col0 + wc * 32 + n * 16 + cl;
                float* obc = out + (size_t)(col >> 8) * NN * CC + (col & 255);
#pragma unroll
                for (int r = 0; r < 4; ++r) {
                    const int i = row0 + wr * 32 + m * 16 + rgrp * 4 + r;  // 0..255
                    const float v = acc[m][n][r];
                    if (half == 0) {
                        obc[(size_t)(4 * i) * CC] = v;
                        if (i >= 1) obc[(size_t)(2048 - 4 * i) * CC] = v;
                    } else {
                        obc[(size_t)(4 * i + 2) * CC] = v;
                        obc[(size_t)(2046 - 4 * i) * CC] = v;
                    }
                }
            }
    }
}

// ---------------- fallback (no/small ws): correct but slow ----------------

__global__ void fallback_kernel(const float* __restrict__ x, float* __restrict__ out) {
    __shared__ float tbl[NN];
    const int b = blockIdx.y;
    const int kbase = blockIdx.x * 16;
    const int t = threadIdx.x;  // 256 = C
    for (int i = t; i < NN; i += 256)
        tbl[i] = cosf((float)i * ANG2);
    __syncthreads();
    float acc[16];
#pragma unroll
    for (int kk = 0; kk < 16; ++kk) acc[kk] = 0.f;
    const float* xb = x + (size_t)b * NN * CC;
    for (int n = 0; n < NN; ++n) {
        const float xv = xb[(size_t)n * CC + t];
#pragma unroll
        for (int kk = 0; kk < 16; ++kk) {
            const int m = (n * (kbase + kk)) & (NN - 1);
            acc[kk] += tbl[m] * xv;
        }
    }
#pragma unroll
    for (int kk = 0; kk < 16; ++kk)
        out[((size_t)b * NN + kbase + kk) * CC + t] = acc[kk];
}

extern "C" void kernel_launch(void* const* d_in, const int* in_sizes, int n_in,
                              void* d_out, int out_size, void* d_ws, size_t ws_size,
                              hipStream_t stream) {
    const float* x = (const float*)d_in[0];
    float* out = (float*)d_out;

    const size_t Aee_b = (size_t)MEE * KEE * 2;      // 163,840
    const size_t Aeo_b = (size_t)256 * KEO * 2;      // 131,072
    const size_t Ao_b  = (size_t)512 * KO  * 2;      // 524,288
    const size_t Yee_b = (size_t)COLS * KEE * 2;     // 2,621,440
    const size_t Yeo_b = (size_t)COLS * KEO * 2;     // 2,097,152
    const size_t Yo_b  = (size_t)COLS * KO  * 2;     // 4,194,304
    const size_t need = Aee_b + Aeo_b + Ao_b + Yee_b + Yeo_b + Yo_b;

    if (ws_size >= need) {
        char* p = (char*)d_ws;
        bf16_t* Aee = (bf16_t*)p;              p += Aee_b;
        bf16_t* Aeo = (bf16_t*)p;              p += Aeo_b;
        bf16_t* Ao  = (bf16_t*)p;              p += Ao_b;
        bf16_t* Yee = (bf16_t*)p;              p += Yee_b;
        bf16_t* Yeo = (bf16_t*)p;              p += Yeo_b;
        bf16_t* Yo  = (bf16_t*)p;
        prep_kernel<<<PREP_BLOCKS, 256, 0, stream>>>(x, Aee, Aeo, Ao, Yee, Yeo, Yo);
        gemm_kernel<<<dim3(COLS / 64, 13), 256, 0, stream>>>(Aee, Aeo, Ao, Yee, Yeo, Yo, out);
    } else {
        fallback_kernel<<<dim3(NN / 16, BB), CC, 0, stream>>>(x, out);
    }
}

// Round 6
// 26.831 us; speedup vs baseline: 1.1758x; 1.0505x over previous
//
#include <hip/hip_runtime.h>
#include <hip/hip_bf16.h>
#include <math.h>

typedef __bf16 bf16_t;
typedef __attribute__((ext_vector_type(8))) __bf16 bf16x8;
typedef __attribute__((ext_vector_type(4))) float f32x4;

#define NN 2048
#define CC 256
#define BB 16
#define COLS 4096          // flattened (b,c)

// Sub-transforms (out[k], k=0..2047):
//  EE: out[4i]   = sum_{p=0}^{256} ee[p] cos(2pi*p*i/512),       i=0..255 (+mirror 2048-4i; k=1024 via GEMV)
//  EO: out[4i+2] = sum_{m=0}^{255} eo[m] cos(2pi*m*(2i+1)/1024), i=0..255 (+mirror 2046-4i)
//  O : out[2j+1] = sum_{m=0}^{511} o[m]  cos(2pi*m*(2j+1)/2048), j=0..511 (+mirror 2047-2j)
//  O K-axis is PERMUTED: u<256 -> m=u ; u==256 -> m=256 ; u>256 -> m=768-u
#define KEE 320            // 257 padded to 5*64
#define MEE 256
#define KEO 256
#define KO  512

#define ANG2 (6.283185307179586f / 2048.0f)
#define ANG1 (6.283185307179586f / 1024.0f)
#define ANG0 (6.283185307179586f / 512.0f)

__device__ __forceinline__ void gload_lds16(const void* g, void* l) {
    __builtin_amdgcn_global_load_lds(
        (const __attribute__((address_space(1))) void*)g,
        (__attribute__((address_space(3))) void*)l, 16, 0, 0);
}

union V8 { bf16_t h[8]; uint4 v; };

// ---------------- prologue: A-build + register-only fold ----------------
// blocks: [0,40) Aee | [40,72) Aeo | [72,200) Ao | [200,712) fold | [712,776) p=256
#define NBLK_AEE 40
#define NBLK_AEO 32
#define NBLK_AO  128
#define NBLK_A   (NBLK_AEE + NBLK_AEO + NBLK_AO)
#define NBLK_FOLD 512
#define PREP_BLOCKS (NBLK_A + NBLK_FOLD + 64)

__global__ __launch_bounds__(256) void prep_kernel(
    const float* __restrict__ x,
    bf16_t* __restrict__ Aee, bf16_t* __restrict__ Aeo, bf16_t* __restrict__ Ao,
    bf16_t* __restrict__ Yee, bf16_t* __restrict__ Yeo, bf16_t* __restrict__ Yo)
{
    const int blk = blockIdx.x;
    const int t = threadIdx.x;

    if (blk < NBLK_AEE) {              // Aee[i][p] = cos(2pi*p*i/512), zero p>256
        const int u = blk * 256 + t;
        const int i = u / 40;
        const int p0 = (u - i * 40) * 8;
        const unsigned step = (unsigned)i & 511u;
        unsigned ph = ((unsigned)i * (unsigned)p0) & 511u;
        V8 vals;
#pragma unroll
        for (int q = 0; q < 8; ++q) {
            vals.h[q] = (p0 + q <= 256) ? (bf16_t)cosf((float)ph * ANG0) : (bf16_t)0.0f;
            ph = (ph + step) & 511u;
        }
        *reinterpret_cast<uint4*>(Aee + (size_t)i * KEE + p0) = vals.v;
        return;
    }
    if (blk < NBLK_AEE + NBLK_AEO) {   // Aeo[i][m] = cos(2pi*m*(2i+1)/1024)
        const int u = (blk - NBLK_AEE) * 256 + t;
        const int i = u >> 5;
        const int m0 = (u & 31) * 8;
        const unsigned tw = 2u * (unsigned)i + 1u;
        unsigned ph = ((unsigned)m0 * tw) & 1023u;
        V8 vals;
#pragma unroll
        for (int q = 0; q < 8; ++q) {
            vals.h[q] = (bf16_t)cosf((float)ph * ANG1);
            ph = (ph + tw) & 1023u;
        }
        *reinterpret_cast<uint4*>(Aeo + (size_t)i * KEO + m0) = vals.v;
        return;
    }
    if (blk < NBLK_A) {                // Ao[j][u] = cos(2pi*m(u)*(2j+1)/2048)
        const int u = (blk - NBLK_AEE - NBLK_AEO) * 256 + t;
        const int j = u >> 6;
        const int u0 = (u & 63) * 8;
        const unsigned tw = 2u * (unsigned)j + 1u;
        V8 vals;
#pragma unroll
        for (int q = 0; q < 8; ++q) {
            const int uu = u0 + q;
            const int m = (uu <= 256) ? uu : (768 - uu);
            const unsigned ph = ((unsigned)m * tw) & 2047u;
            vals.h[q] = (bf16_t)cosf((float)ph * ANG2);
        }
        *reinterpret_cast<uint4*>(Ao + (size_t)j * KO + u0) = vals.v;
        return;
    }

    if (blk < NBLK_A + NBLK_FOLD) {
        // ---- fold: (p-tile, col-tile), all register, all aligned ----
        const int f = blk - NBLK_A;
        const int pt = f >> 6;             // 0..7
        const int ct = f & 63;             // 0..63
        const int gc0 = ct * 64;
        const int col = t & 63;
        const int pg = t >> 6;             // wave id 0..3
        const int p_base = pt * 32 + pg * 8;
        const float* xcol = x + (size_t)(gc0 >> 8) * NN * CC + (gc0 & 255) + col;

        float eeV[8], eoV[8], olV[8], ohV[8];
#pragma unroll
        for (int q = 0; q < 8; ++q) {
            const int p = p_base + q;
            const int n2 = 512 - p, n3 = 512 + p, n4 = 1024 - p;
            const int n5 = 1024 + p, n6 = 1536 - p, n7 = 1536 + p;
            const int n8 = (2048 - p) & 2047;
            const float x1 = xcol[(size_t)p  * CC];
            const float x2 = xcol[(size_t)n2 * CC];
            const float x3 = xcol[(size_t)n3 * CC];
            const float x4 = xcol[(size_t)n4 * CC];
            const float x5 = xcol[(size_t)n5 * CC];
            const float x6 = xcol[(size_t)n6 * CC];
            const float x7 = xcol[(size_t)n7 * CC];
            const float x8 = xcol[(size_t)n8 * CC];
            const float w = (p == 0) ? 0.5f : 1.0f;
            const float e_lo = w * ((x1 + x4) + (x5 + x8));
            const float e_hi = w * ((x2 + x3) + (x6 + x7));
            olV[q] = w * ((x1 - x5) - (x4 - x8));
            ohV[q] = (x2 - x6) - (x3 - x7);       // o[512-p] -> slot u=256+p
            eeV[q] = e_lo + e_hi;
            eoV[q] = e_lo - e_hi;
        }
        if (pt == 0 && pg == 0) {
            // p==0 lane: oh slot u=256 must carry o[256] (o[512] doesn't exist)
            const float a = xcol[(size_t)256  * CC];
            const float b2 = xcol[(size_t)768  * CC];
            const float c = xcol[(size_t)1280 * CC];
            const float d = xcol[(size_t)1792 * CC];
            ohV[0] = (a - c) - (b2 - d);
        }
        V8 vee, veo, vol, voh;
#pragma unroll
        for (int q = 0; q < 8; ++q) {
            vee.h[q] = (bf16_t)eeV[q]; veo.h[q] = (bf16_t)eoV[q];
            vol.h[q] = (bf16_t)olV[q]; voh.h[q] = (bf16_t)ohV[q];
        }
        const size_t gcol = (size_t)(gc0 + col);
        *reinterpret_cast<uint4*>(Yee + gcol * KEE + p_base) = vee.v;
        *reinterpret_cast<uint4*>(Yeo + gcol * KEO + p_base) = veo.v;
        *reinterpret_cast<uint4*>(Yo  + gcol * KO  + p_base) = vol.v;
        *reinterpret_cast<uint4*>(Yo  + gcol * KO  + 256 + p_base) = voh.v;
        return;
    }

    // ---- p=256 tile: ee[256] + zero-fill Yee[257..319] ----
    {
        const int ct = blk - (NBLK_A + NBLK_FOLD);
        if (t >= 64) return;
        const int gc0 = ct * 64;
        const float* xcol = x + (size_t)(gc0 >> 8) * NN * CC + (gc0 & 255) + t;
        const float ee256 = (xcol[(size_t)256 * CC] + xcol[(size_t)768 * CC]) +
                            (xcol[(size_t)1280 * CC] + xcol[(size_t)1792 * CC]);
        bf16_t* base = Yee + (size_t)(gc0 + t) * KEE + 256;
        V8 z; z.v = make_uint4(0, 0, 0, 0);
        V8 first = z; first.h[0] = (bf16_t)ee256;
        *reinterpret_cast<uint4*>(base) = first.v;
#pragma unroll
        for (int ch = 1; ch < 8; ++ch)
            *reinterpret_cast<uint4*>(base + ch * 8) = z.v;
    }
}

// ---------------- triple GEMM + GEMV, one launch ----------------
// grid (64, 13): y 0..3 EE (BM=64), 4..7 EO (BM=64), 8..11 O (BM=128), 12 GEMV.
// Double-buffered LDS prefetch (T3-minimum) + XOR chunk-swizzle (T2, rule 21):
// gload_lds dest stays LINEAR; global source chunk ^= (row&7); ds_read applies
// the same XOR. Kills the 16-way conflict of the 128B-stride row-major tile.

__global__ __launch_bounds__(256) void gemm_kernel(
    const bf16_t* __restrict__ Aee, const bf16_t* __restrict__ Aeo,
    const bf16_t* __restrict__ Ao,
    const bf16_t* __restrict__ Yee, const bf16_t* __restrict__ Yeo,
    const bf16_t* __restrict__ Yo, float* __restrict__ out)
{
    __shared__ bf16_t As[2][128 * 64];   // 32 KB
    __shared__ bf16_t Bs[2][64 * 64];    // 16 KB
    __shared__ float red[64][4];

    const int col0 = blockIdx.x * 64;
    const int yb = blockIdx.y;
    const int t = threadIdx.x;

    if (yb == 12) {                    // ---- GEMV: out[1024][c] = sum (-1)^p ee[p]
        const int col = t & 63;
        const int part = t >> 6;
        const bf16_t* yc = Yee + (size_t)(col0 + col) * KEE + part * 80;
        float s = 0.f;
#pragma unroll
        for (int jc = 0; jc < 10; ++jc) {
            const bf16x8 v = *reinterpret_cast<const bf16x8*>(yc + jc * 8);
#pragma unroll
            for (int q = 0; q < 8; ++q)
                s += (q & 1) ? -(float)v[q] : (float)v[q];
        }
        red[col][part] = s;
        __syncthreads();
        if (t < 64) {
            const float tot = (red[t][0] + red[t][1]) + (red[t][2] + red[t][3]);
            const int gc = col0 + t;
            out[(size_t)(gc >> 8) * NN * CC + (size_t)1024 * CC + (gc & 255)] = tot;
        }
        return;
    }

    const bf16_t *Ab, *Bb;
    int row0, kdim, half;
    if (yb < 4)      { half = 0; row0 = yb * 64;        kdim = KEE; Ab = Aee + (size_t)row0 * KEE; Bb = Yee + (size_t)col0 * KEE; }
    else if (yb < 8) { half = 1; row0 = (yb - 4) * 64;  kdim = KEO; Ab = Aeo + (size_t)row0 * KEO; Bb = Yeo + (size_t)col0 * KEO; }
    else             { half = 2; row0 = (yb - 8) * 128; kdim = KO;  Ab = Ao  + (size_t)row0 * KO;  Bb = Yo  + (size_t)col0 * KO; }
    const int ksteps = kdim >> 6;

    const int lane = t & 63;
    const int wid = t >> 6;
    const int wr = wid >> 1, wc = wid & 1;
    const int srow = t >> 3;             // 0..31
    const int sc_chunk = t & 7;          // 16B-chunk index within the 64-elem row
    const int s_swz = (sc_chunk ^ (srow & 7)) * 8;   // swizzled source elem offset
    const int lds_lin = srow * 64 + sc_chunk * 8;    // linear dest elem offset
    const int lrow = lane & 15;
    const int rx8 = lrow & 7;            // read-side swizzle key
    const int rgrp = lane >> 4;
    const int cl = lane & 15;
    const int hi8 = (lane >> 4) * 8;     // koff base within kk-group

    if (half == 2) {                   // ---- O: BM=128, ksteps=8 ----
        f32x4 acc[4][2] = {};
        int cur = 0;
        // prologue stage k-step 0 into buf 0
#pragma unroll
        for (int it = 0; it < 4; ++it)
            gload_lds16(Ab + (size_t)(srow + it * 32) * KO + s_swz,
                        &As[0][lds_lin + it * 2048]);
#pragma unroll
        for (int it = 0; it < 2; ++it)
            gload_lds16(Bb + (size_t)(srow + it * 32) * KO + s_swz,
                        &Bs[0][lds_lin + it * 2048]);
        __syncthreads();
        for (int kt = 0; kt < 8; ++kt) {
            if (kt + 1 < 8) {
                const int k0 = (kt + 1) * 64;
#pragma unroll
                for (int it = 0; it < 4; ++it)
                    gload_lds16(Ab + (size_t)(srow + it * 32) * KO + k0 + s_swz,
                                &As[cur ^ 1][lds_lin + it * 2048]);
#pragma unroll
                for (int it = 0; it < 2; ++it)
                    gload_lds16(Bb + (size_t)(srow + it * 32) * KO + k0 + s_swz,
                                &Bs[cur ^ 1][lds_lin + it * 2048]);
            }
            const bf16_t* as = &As[cur][0];
            const bf16_t* bs = &Bs[cur][0];
#pragma unroll
            for (int kk = 0; kk < 64; kk += 32) {
                const int g = (kk + hi8) >> 3;           // global chunk 0..7
                const int rc = ((g ^ rx8) * 8);          // swizzled read offset
                bf16x8 af[4], bfr[2];
#pragma unroll
                for (int m = 0; m < 4; ++m)
                    af[m] = *(const bf16x8*)&as[(wr * 64 + m * 16 + lrow) * 64 + rc];
#pragma unroll
                for (int n = 0; n < 2; ++n)
                    bfr[n] = *(const bf16x8*)&bs[(wc * 32 + n * 16 + lrow) * 64 + rc];
#pragma unroll
                for (int m = 0; m < 4; ++m)
#pragma unroll
                    for (int n = 0; n < 2; ++n)
                        acc[m][n] = __builtin_amdgcn_mfma_f32_16x16x32_bf16(
                            af[m], bfr[n], acc[m][n], 0, 0, 0);
            }
            __syncthreads();
            cur ^= 1;
        }
#pragma unroll
        for (int m = 0; m < 4; ++m)
#pragma unroll
            for (int n = 0; n < 2; ++n) {
                const int col = col0 + wc * 32 + n * 16 + cl;
                float* obc = out + (size_t)(col >> 8) * NN * CC + (col & 255);
#pragma unroll
                for (int r = 0; r < 4; ++r) {
                    const int j = row0 + wr * 64 + m * 16 + rgrp * 4 + r;
                    const float v = acc[m][n][r];
                    obc[(size_t)(2 * j + 1) * CC] = v;
                    obc[(size_t)(2047 - 2 * j) * CC] = v;
                }
            }
    } else {                           // ---- EE / EO: BM=64 ----
        f32x4 acc[2][2] = {};
        int cur = 0;
#pragma unroll
        for (int it = 0; it < 2; ++it) {
            const size_t ro = (size_t)(srow + it * 32) * kdim + s_swz;
            gload_lds16(Ab + ro, &As[0][lds_lin + it * 2048]);
            gload_lds16(Bb + ro, &Bs[0][lds_lin + it * 2048]);
        }
        __syncthreads();
        for (int kt = 0; kt < ksteps; ++kt) {
            if (kt + 1 < ksteps) {
                const int k0 = (kt + 1) * 64;
#pragma unroll
                for (int it = 0; it < 2; ++it) {
                    const size_t ro = (size_t)(srow + it * 32) * kdim + k0 + s_swz;
                    gload_lds16(Ab + ro, &As[cur ^ 1][lds_lin + it * 2048]);
                    gload_lds16(Bb + ro, &Bs[cur ^ 1][lds_lin + it * 2048]);
                }
            }
            const bf16_t* as = &As[cur][0];
            const bf16_t* bs = &Bs[cur][0];
#pragma unroll
            for (int kk = 0; kk < 64; kk += 32) {
                const int g = (kk + hi8) >> 3;
                const int rc = ((g ^ rx8) * 8);
                bf16x8 af[2], bfr[2];
#pragma unroll
                for (int m = 0; m < 2; ++m)
                    af[m] = *(const bf16x8*)&as[(wr * 32 + m * 16 + lrow) * 64 + rc];
#pragma unroll
                for (int n = 0; n < 2; ++n)
                    bfr[n] = *(const bf16x8*)&bs[(wc * 32 + n * 16 + lrow) * 64 + rc];
#pragma unroll
                for (int m = 0; m < 2; ++m)
#pragma unroll
                    for (int n = 0; n < 2; ++n)
                        acc[m][n] = __builtin_amdgcn_mfma_f32_16x16x32_bf16(
                            af[m], bfr[n], acc[m][n], 0, 0, 0);
            }
            __syncthreads();
            cur ^= 1;
        }
#pragma unroll
        for (int m = 0; m < 2; ++m)
#pragma unroll
            for (int n = 0; n < 2; ++n) {
                const int col = col0 + wc * 32 + n * 16 + cl;
                float* obc = out + (size_t)(col >> 8) * NN * CC + (col & 255);
#pragma unroll
                for (int r = 0; r < 4; ++r) {
                    const int i = row0 + wr * 32 + m * 16 + rgrp * 4 + r;  // 0..255
                    const float v = acc[m][n][r];
                    if (half == 0) {
                        obc[(size_t)(4 * i) * CC] = v;
                        if (i >= 1) obc[(size_t)(2048 - 4 * i) * CC] = v;
                    } else {
                        obc[(size_t)(4 * i + 2) * CC] = v;
                        obc[(size_t)(2046 - 4 * i) * CC] = v;
                    }
                }
            }
    }
}

// ---------------- fallback (no/small ws): correct but slow ----------------

__global__ void fallback_kernel(const float* __restrict__ x, float* __restrict__ out) {
    __shared__ float tbl[NN];
    const int b = blockIdx.y;
    const int kbase = blockIdx.x * 16;
    const int t = threadIdx.x;  // 256 = C
    for (int i = t; i < NN; i += 256)
        tbl[i] = cosf((float)i * ANG2);
    __syncthreads();
    float acc[16];
#pragma unroll
    for (int kk = 0; kk < 16; ++kk) acc[kk] = 0.f;
    const float* xb = x + (size_t)b * NN * CC;
    for (int n = 0; n < NN; ++n) {
        const float xv = xb[(size_t)n * CC + t];
#pragma unroll
        for (int kk = 0; kk < 16; ++kk) {
            const int m = (n * (kbase + kk)) & (NN - 1);
            acc[kk] += tbl[m] * xv;
        }
    }
#pragma unroll
    for (int kk = 0; kk < 16; ++kk)
        out[((size_t)b * NN + kbase + kk) * CC + t] = acc[kk];
}

extern "C" void kernel_launch(void* const* d_in, const int* in_sizes, int n_in,
                              void* d_out, int out_size, void* d_ws, size_t ws_size,
                              hipStream_t stream) {
    const float* x = (const float*)d_in[0];
    float* out = (float*)d_out;

    const size_t Aee_b = (size_t)MEE * KEE * 2;      // 163,840
    const size_t Aeo_b = (size_t)256 * KEO * 2;      // 131,072
    const size_t Ao_b  = (size_t)512 * KO  * 2;      // 524,288
    const size_t Yee_b = (size_t)COLS * KEE * 2;     // 2,621,440
    const size_t Yeo_b = (size_t)COLS * KEO * 2;     // 2,097,152
    const size_t Yo_b  = (size_t)COLS * KO  * 2;     // 4,194,304
    const size_t need = Aee_b + Aeo_b + Ao_b + Yee_b + Yeo_b + Yo_b;

    if (ws_size >= need) {
        char* p = (char*)d_ws;
        bf16_t* Aee = (bf16_t*)p;              p += Aee_b;
        bf16_t* Aeo = (bf16_t*)p;              p += Aeo_b;
        bf16_t* Ao  = (bf16_t*)p;              p += Ao_b;
        bf16_t* Yee = (bf16_t*)p;              p += Yee_b;
        bf16_t* Yeo = (bf16_t*)p;              p += Yeo_b;
        bf16_t* Yo  = (bf16_t*)p;
        prep_kernel<<<PREP_BLOCKS, 256, 0, stream>>>(x, Aee, Aeo, Ao, Yee, Yeo, Yo);
        gemm_kernel<<<dim3(COLS / 64, 13), 256, 0, stream>>>(Aee, Aeo, Ao, Yee, Yeo, Yo, out);
    } else {
        fallback_kernel<<<dim3(NN / 16, BB), CC, 0, stream>>>(x, out);
    }
}